// Round 4
// baseline (100.843 us; speedup 1.0000x reference)
//
#include <hip/hip_runtime.h>
#include <hip/hip_bf16.h>
#include <stdint.h>

#define NB    32
#define CIN   128
#define HIN   56
#define HW    (HIN*HIN)     // 3136
#define OCH   256
#define OHW   54
#define SPB   (OHW*OHW)     // 2916
#define KSZ   (CIN*9)       // 1152 = GEMM K
#define BM    128           // oc rows per block
#define BN    256           // flattened (n,sp) cols per block
#define BK    64
#define NKS   (KSZ/BK)      // 18 K-tiles
#define TOTC  (NB*SPB)      // 93312
#define NT    365           // ceil(93312/256)

typedef __attribute__((ext_vector_type(8))) short bf16x8;
typedef __attribute__((ext_vector_type(4))) float f32x4;

typedef __attribute__((address_space(1))) const uint32_t g_u32;
typedef __attribute__((address_space(3))) uint32_t l_u32;
static __device__ __forceinline__ void gl_lds16(const void* g, void* l) {
    __builtin_amdgcn_global_load_lds((g_u32*)g, (l_u32*)l, 16, 0, 0);
}

// ---- pre-pass 1: x NCHW f32 -> NHWC bf16 ----
__global__ void xpose_cast(const float* __restrict__ x, __hip_bfloat16* __restrict__ xt) {
    __shared__ float tile[32][33];
    const int hw0 = blockIdx.x * 32;
    const int c0  = blockIdx.y * 32;
    const int n   = blockIdx.z;
    const int tx = threadIdx.x, ty = threadIdx.y;
    const float* xp = x + ((size_t)n*CIN + c0)*HW + hw0;
    #pragma unroll
    for (int i = ty; i < 32; i += 8)
        tile[i][tx] = xp[(size_t)i*HW + tx];
    __syncthreads();
    const int t = ty*32 + tx;
    const int hwl = t >> 3, q = t & 7;
    ushort4 v;
    v.x = __bfloat16_as_ushort(__float2bfloat16(tile[q*4+0][hwl]));
    v.y = __bfloat16_as_ushort(__float2bfloat16(tile[q*4+1][hwl]));
    v.z = __bfloat16_as_ushort(__float2bfloat16(tile[q*4+2][hwl]));
    v.w = __bfloat16_as_ushort(__float2bfloat16(tile[q*4+3][hwl]));
    __hip_bfloat16* op = xt + ((size_t)n*HW + hw0 + hwl)*CIN + c0 + q*4;
    *(ushort4*)op = v;
}

// ---- pre-pass 2: weight OIHW f32 -> [oc][(kh*3+kw)*128+ic] bf16 ----
__global__ void wcast(const float* __restrict__ w, __hip_bfloat16* __restrict__ wt) {
    int tid = blockIdx.x*256 + threadIdx.x;
    if (tid >= OCH*KSZ) return;
    int oc = tid / KSZ, r = tid % KSZ;
    int pos = r >> 7, ic = r & 127;
    wt[tid] = __float2bfloat16(w[((size_t)(oc*CIN + ic))*9 + pos]);
}

// ---- main: implicit-GEMM bf16 MFMA conv, 4-phase/K-tile m201-style schedule ----
// grid (365, 2), block 512 (8 waves = 2M x 4N of 64x64)
__global__ __launch_bounds__(512, 2)
void conv_mfma(const __hip_bfloat16* __restrict__ xt,
               const __hip_bfloat16* __restrict__ wt,
               const float* __restrict__ bias,
               float* __restrict__ out) {
    // 3 buffers x (A 128x64 + B 256x64 bf16) = 144KB; granule-XOR swizzle
    __shared__ uint4 smem[3*3072];

    const int t = threadIdx.x;
    const int tile = blockIdx.x, octile = blockIdx.y;
    const int lane = t & 63, wid = t >> 6;
    const int wm = wid >> 2, wn = wid & 3;
    const int lr = lane & 15, lq = lane >> 4;

    const __hip_bfloat16* asrc[2];
    #pragma unroll
    for (int i = 0; i < 2; ++i) {
        int p = i*512 + t;
        int row = p >> 3, g = (p & 7) ^ (row & 7);
        asrc[i] = wt + (size_t)(octile*BM + row)*KSZ + g*8;
    }
    const __hip_bfloat16* bsrc[4];
    #pragma unroll
    for (int i = 0; i < 4; ++i) {
        int p = i*512 + t;
        int row = p >> 3, g = (p & 7) ^ (row & 7);
        int colg = tile*BN + row; if (colg >= TOTC) colg = TOTC - 1;
        int n = colg / SPB, rem = colg - n*SPB;
        int oh = rem / OHW, ow = rem - oh*OHW;
        bsrc[i] = xt + ((size_t)(n*HIN + oh)*HIN + ow)*CIN + g*8;
    }

    // stage units: 0 = A (2 loads), 1 = B0 (2), 2 = B1 (2)
    auto issueU = [&](int ks, int unit) {
        uint4* Ab = smem + (ks % 3)*3072;
        uint4* Bb = Ab + 1024;
        const int pos = ks >> 1;
        const int kh = pos / 3, kw = pos - kh*3;
        const int aoff = ks*BK;
        const int boff = (kh*HIN + kw)*CIN + (ks & 1)*64;
        if (unit == 0) {
            gl_lds16(asrc[0] + aoff, Ab + t);
            gl_lds16(asrc[1] + aoff, Ab + 512 + t);
        } else if (unit == 1) {
            gl_lds16(bsrc[0] + boff, Bb + t);
            gl_lds16(bsrc[1] + boff, Bb + 512 + t);
        } else {
            gl_lds16(bsrc[2] + boff, Bb + 1024 + t);
            gl_lds16(bsrc[3] + boff, Bb + 1536 + t);
        }
    };

    f32x4 acc[4][4];
    #pragma unroll
    for (int i = 0; i < 4; ++i)
        #pragma unroll
        for (int j = 0; j < 4; ++j)
            acc[i][j] = (f32x4){0.f, 0.f, 0.f, 0.f};

    // prologue: tiles 0 and 1 fully issued (12 loads/thread in flight)
    issueU(0,0); issueU(0,1); issueU(0,2);
    issueU(1,0); issueU(1,1); issueU(1,2);
    asm volatile("s_waitcnt vmcnt(6)" ::: "memory");   // tile 0 landed
    __builtin_amdgcn_s_barrier();

    #define MFMA_BF16 __builtin_amdgcn_mfma_f32_16x16x32_bf16

    for (int ks = 0; ks < NKS; ++ks) {
        const uint4* Ab = smem + (ks % 3)*3072;
        const uint4* Bb = Ab + 1024;
        bf16x8 a0[4], a1[4], bA, bB, bC, bD;

        // ---- phase 0: kk=0, ni=0,1 (6 ds_read) + stage A(ks+2)
        #pragma unroll
        for (int mi = 0; mi < 4; ++mi) {
            int ra = wm*64 + mi*16 + lr;
            a0[mi] = *(bf16x8*)&Ab[ra*8 + (lq ^ (ra & 7))];
        }
        { int rb = wn*64 +  0 + lr; bA = *(bf16x8*)&Bb[rb*8 + (lq ^ (rb & 7))]; }
        { int rb = wn*64 + 16 + lr; bB = *(bf16x8*)&Bb[rb*8 + (lq ^ (rb & 7))]; }
        if (ks + 2 < NKS) issueU(ks + 2, 0);
        __builtin_amdgcn_s_barrier();
        asm volatile("s_waitcnt lgkmcnt(0)");
        __builtin_amdgcn_s_setprio(1);
        #pragma unroll
        for (int mi = 0; mi < 4; ++mi) {
            acc[mi][0] = MFMA_BF16(a0[mi], bA, acc[mi][0], 0, 0, 0);
            acc[mi][1] = MFMA_BF16(a0[mi], bB, acc[mi][1], 0, 0, 0);
        }
        __builtin_amdgcn_s_setprio(0);
        __builtin_amdgcn_s_barrier();

        // ---- phase 1: kk=0, ni=2,3 (2 ds_read) + stage B0(ks+2)
        { int rb = wn*64 + 32 + lr; bC = *(bf16x8*)&Bb[rb*8 + (lq ^ (rb & 7))]; }
        { int rb = wn*64 + 48 + lr; bD = *(bf16x8*)&Bb[rb*8 + (lq ^ (rb & 7))]; }
        if (ks + 2 < NKS) issueU(ks + 2, 1);
        __builtin_amdgcn_s_barrier();
        asm volatile("s_waitcnt lgkmcnt(0)");
        __builtin_amdgcn_s_setprio(1);
        #pragma unroll
        for (int mi = 0; mi < 4; ++mi) {
            acc[mi][2] = MFMA_BF16(a0[mi], bC, acc[mi][2], 0, 0, 0);
            acc[mi][3] = MFMA_BF16(a0[mi], bD, acc[mi][3], 0, 0, 0);
        }
        __builtin_amdgcn_s_setprio(0);
        __builtin_amdgcn_s_barrier();

        // ---- phase 2: kk=1, ni=0,1 (6 ds_read) + stage B1(ks+2)
        #pragma unroll
        for (int mi = 0; mi < 4; ++mi) {
            int ra = wm*64 + mi*16 + lr;
            a1[mi] = *(bf16x8*)&Ab[ra*8 + ((4 + lq) ^ (ra & 7))];
        }
        { int rb = wn*64 +  0 + lr; bA = *(bf16x8*)&Bb[rb*8 + ((4 + lq) ^ (rb & 7))]; }
        { int rb = wn*64 + 16 + lr; bB = *(bf16x8*)&Bb[rb*8 + ((4 + lq) ^ (rb & 7))]; }
        if (ks + 2 < NKS) issueU(ks + 2, 2);
        __builtin_amdgcn_s_barrier();
        asm volatile("s_waitcnt lgkmcnt(0)");
        __builtin_amdgcn_s_setprio(1);
        #pragma unroll
        for (int mi = 0; mi < 4; ++mi) {
            acc[mi][0] = MFMA_BF16(a1[mi], bA, acc[mi][0], 0, 0, 0);
            acc[mi][1] = MFMA_BF16(a1[mi], bB, acc[mi][1], 0, 0, 0);
        }
        __builtin_amdgcn_s_setprio(0);
        __builtin_amdgcn_s_barrier();

        // ---- phase 3: kk=1, ni=2,3 (2 ds_read); vmcnt certifies buf ks+1
        { int rb = wn*64 + 32 + lr; bC = *(bf16x8*)&Bb[rb*8 + ((4 + lq) ^ (rb & 7))]; }
        { int rb = wn*64 + 48 + lr; bD = *(bf16x8*)&Bb[rb*8 + ((4 + lq) ^ (rb & 7))]; }
        __builtin_amdgcn_s_barrier();
        asm volatile("s_waitcnt lgkmcnt(0)");
        __builtin_amdgcn_s_setprio(1);
        #pragma unroll
        for (int mi = 0; mi < 4; ++mi) {
            acc[mi][2] = MFMA_BF16(a1[mi], bC, acc[mi][2], 0, 0, 0);
            acc[mi][3] = MFMA_BF16(a1[mi], bD, acc[mi][3], 0, 0, 0);
        }
        __builtin_amdgcn_s_setprio(0);
        if (ks < NKS-1) {
            if (ks == NKS-2) asm volatile("s_waitcnt vmcnt(0)" ::: "memory");
            else             asm volatile("s_waitcnt vmcnt(6)" ::: "memory");
        }
        __builtin_amdgcn_s_barrier();   // doubles as certify-barrier for buf ks+1
    }

    __syncthreads();

    // --- epilogue: LDS restage [64][260] (row-delta-4 -> 2-way, free), float4 stores
    float (*eps)[260] = (float (*)[260])smem;
    for (int h = 0; h < 2; ++h) {
        if (wm == h) {
            #pragma unroll
            for (int mi = 0; mi < 4; ++mi) {
                int rl = mi*16 + lq*4;
                #pragma unroll
                for (int ni = 0; ni < 4; ++ni) {
                    int cl = wn*64 + ni*16 + lr;
                    #pragma unroll
                    for (int r = 0; r < 4; ++r)
                        eps[rl + r][cl] = acc[mi][ni][r];
                }
            }
        }
        __syncthreads();
        const int cl4 = (t & 63) * 4;
        const int rsub = t >> 6;
        const int colg = tile*BN + cl4;
        if (colg < TOTC) {
            const int n = colg / SPB;
            const int sp = colg - n*SPB;
            #pragma unroll
            for (int pass = 0; pass < 8; ++pass) {
                int rl = pass*8 + rsub;
                int rg = octile*BM + h*64 + rl;
                f32x4 v = *(f32x4*)&eps[rl][cl4];
                v = v + bias[rg];
                *(f32x4*)&out[((size_t)n*OCH + rg)*SPB + sp] = v;
            }
        }
        __syncthreads();
    }
}

// ---- fallback: direct fp32 conv ----
__global__ void conv_naive(const float* __restrict__ x, const float* __restrict__ w,
                           const float* __restrict__ bias, float* __restrict__ out) {
    size_t tid = (size_t)blockIdx.x*256 + threadIdx.x;
    const size_t total = (size_t)NB*OCH*SPB;
    if (tid >= total) return;
    int col = (int)(tid % SPB);
    int oc  = (int)((tid / SPB) % OCH);
    int n   = (int)(tid / ((size_t)SPB*OCH));
    int oh = col / OHW, ow = col % OHW;
    float s = bias[oc];
    for (int ic = 0; ic < CIN; ++ic)
        #pragma unroll
        for (int kh = 0; kh < 3; ++kh)
            #pragma unroll
            for (int kw = 0; kw < 3; ++kw)
                s += x[((size_t)(n*CIN+ic)*HIN + oh+kh)*HIN + ow+kw]
                   * w[((size_t)(oc*CIN+ic)*3 + kh)*3 + kw];
    out[tid] = s;
}

extern "C" void kernel_launch(void* const* d_in, const int* in_sizes, int n_in,
                              void* d_out, int out_size, void* d_ws, size_t ws_size,
                              hipStream_t stream) {
    const float* x    = (const float*)d_in[0];
    const float* w    = (const float*)d_in[1];
    const float* bias = (const float*)d_in[2];
    float* out = (float*)d_out;

    const size_t xt_bytes = (size_t)NB*HW*CIN*sizeof(__hip_bfloat16);
    const size_t wt_bytes = (size_t)OCH*KSZ*sizeof(__hip_bfloat16);

    if (ws_size >= xt_bytes + wt_bytes) {
        __hip_bfloat16* xt  = (__hip_bfloat16*)d_ws;
        __hip_bfloat16* wtp = (__hip_bfloat16*)((char*)d_ws + xt_bytes);
        hipLaunchKernelGGL(xpose_cast, dim3(HW/32, CIN/32, NB), dim3(32, 8), 0, stream, x, xt);
        hipLaunchKernelGGL(wcast, dim3((OCH*KSZ + 255)/256), dim3(256), 0, stream, w, wtp);
        hipLaunchKernelGGL(conv_mfma, dim3(NT, OCH/BM), dim3(512), 0, stream,
                           xt, wtp, bias, out);
    } else {
        size_t total = (size_t)NB*OCH*SPB;
        hipLaunchKernelGGL(conv_naive, dim3((unsigned)((total + 255)/256)), dim3(256), 0, stream,
                           x, w, bias, out);
    }
}